// Round 5
// baseline (4797.570 us; speedup 1.0000x reference)
//
#include <hip/hip_runtime.h>

// Problem constants
#define B_ 64
#define T_ 512
#define DIN_ 256
#define N_ 1024
#define O_ 128

using half8 = __attribute__((ext_vector_type(8))) _Float16;
using f32x4 = __attribute__((ext_vector_type(4))) float;
typedef unsigned long long ull;

__device__ __forceinline__ half8 cvt8(float4 a, float4 b) {
    half8 h;
    h[0] = (_Float16)a.x; h[1] = (_Float16)a.y; h[2] = (_Float16)a.z; h[3] = (_Float16)a.w;
    h[4] = (_Float16)b.x; h[5] = (_Float16)b.y; h[6] = (_Float16)b.z; h[7] = (_Float16)b.w;
    return h;
}

__device__ __forceinline__ float fast_tanh(float x) {
    float ax = __builtin_fabsf(x);
    float e  = __expf(-2.0f * ax);
    float r  = __fdividef(1.0f - e, 1.0f + e);
    return x < 0.0f ? -r : r;
}

// 16B A-fragment load as two 8B agent-scope atomic loads (L1-bypassing,
// R2-verified primitive). kb/li arithmetic folds at compile time.
__device__ __forceinline__ half8 ldh8(const ull* ep, int kb, int li) {
    union { ull q[2]; half8 h; } ua;
    ua.q[0] = __hip_atomic_load(&ep[kb * 128 + li],     __ATOMIC_RELAXED, __HIP_MEMORY_SCOPE_AGENT);
    ua.q[1] = __hip_atomic_load(&ep[kb * 128 + li + 1], __ATOMIC_RELAXED, __HIP_MEMORY_SCOPE_AGENT);
    return ua.h;
}

// ---------------------------------------------------------------------------
// Zero the 256 per-wave sentinels (only 4*64 used). Sentinels are monotone
// step tags; 0 never satisfies want >= 1, so no stale-accept across launches.
// ---------------------------------------------------------------------------
__global__ void init_kernel(unsigned int* sent) {
    sent[threadIdx.x] = 0u;
}

// ---------------------------------------------------------------------------
// Persistent recurrence, R5: PER-WAVE DECOUPLED loop (no in-loop barriers,
// no LDS staging). 32 blocks = 4 batch-slabs (bs) x 8 col-groups (cg);
// block = 8 waves; wave w owns 16 output cols, W slab (128 VGPR fp16) +
// Win slab (32 VGPR) register-resident.
//
// Exchange: fp16, MFMA A-fragment order (half addr = kb*512 + lane*8 + j).
// Each wave reads its A-fragments DIRECTLY from exch (16B/lane per kb,
// perfectly coalesced, register double-buffered per 4-kb group) — the old
// global->reg->LDS->barrier staging pipeline and both per-step s_barriers
// are gone; waves free-run, eliminating block-lockstep straggler costs.
//
// Publish: wave-private LDS transpose (4x ds_write_b16 -> lgkmcnt(0) ->
// 8B read) then ONE coalesced 8B agent store per lane into the wave's
// contiguous 512B frag-order region; s_waitcnt vmcnt(0) acks the wave's
// store; lane0 then stores the per-wave sentinel sent[cg*8+wave] = t.
//
// Safety (per-wave form of the R2 argument): sentinel(w)=t is stored after
// w's MFMAs consumed its step-t-1 loads (register dependency), so those
// loads completed. Any producer writes step t+1 (same buffer parity as
// t-1) only after seeing ALL 64 sentinels >= t, hence after every wave
// finished reading buffer t-1 — no wanted location is ever overwritten.
// Detect uses >= because fast producers may already have published t.
// ---------------------------------------------------------------------------
__global__ __launch_bounds__(512, 1) void rnn_kernel(
    const float* __restrict__ X,      // [B][T][DIN]
    const float* __restrict__ W,      // [N][N]
    const float* __restrict__ Win,    // [DIN][N]
    float* __restrict__ s_out,        // [B][T][N]
    _Float16* __restrict__ exch,      // [4][2][16384] fp16, frag order
    unsigned int* __restrict__ sent)  // [4][64] per-wave sentinels
{
    const int bs   = blockIdx.x & 3;
    const int cg   = blockIdx.x >> 2;     // 0..7
    const int tid  = threadIdx.x;
    const int wave = tid >> 6;            // 0..7
    const int lane = tid & 63;
    const int l15  = lane & 15;
    const int quad = lane >> 4;
    const int col0 = cg * 128 + wave * 16;
    const int arow = bs * 16 + l15;       // A-frag batch row
    const int crow = bs * 16 + quad * 4;  // C-frag base batch row

    __shared__ __align__(16) _Float16 slab[16 * 1032];  // setup staging + publish transpose

    // ---- one-time: W B-fragments (8 passes, one per wave)
    half8 wf[32];
    for (int p = 0; p < 8; ++p) {
        const int c = tid & 15, k0 = tid >> 4;
        const int wc = cg * 128 + p * 16 + c;
        for (int k = k0; k < N_; k += 32)
            slab[c * 1032 + k] = (_Float16)W[(size_t)k * N_ + wc];
        __syncthreads();
        if (wave == p) {
            #pragma unroll
            for (int kb = 0; kb < 32; ++kb)
                wf[kb] = *(const half8*)&slab[l15 * 1032 + kb * 32 + quad * 8];
        }
        __syncthreads();
    }
    // ---- one-time: Win B-fragments
    half8 winf[8];
    for (int p = 0; p < 8; ++p) {
        const int c = tid & 15, k0 = tid >> 4;
        const int wc = cg * 128 + p * 16 + c;
        for (int k = k0; k < DIN_; k += 32)
            slab[c * 1032 + k] = (_Float16)Win[(size_t)k * N_ + wc];
        __syncthreads();
        if (wave == p) {
            #pragma unroll
            for (int kb = 0; kb < 8; ++kb)
                winf[kb] = *(const half8*)&slab[l15 * 1032 + kb * 32 + quad * 8];
        }
        __syncthreads();
    }

    // ---- s[:,0,:] = 0 for this block's 16r x 128c slice
    #pragma unroll
    for (int i = 0; i < 4; ++i) {
        int e = i * 512 + tid;
        int r = e >> 7, c = e & 127;
        s_out[(size_t)(bs * 16 + r) * T_ * N_ + cg * 128 + c] = 0.0f;
    }

    // ---- u_1 = X[:,0,:] @ Win
    f32x4 u = {0.f, 0.f, 0.f, 0.f};
    {
        const float* xp = X + (size_t)arow * T_ * DIN_ + quad * 8;
        #pragma unroll
        for (int kb = 0; kb < 8; ++kb) {
            float4 x0 = *(const float4*)(xp + kb * 32);
            float4 x1 = *(const float4*)(xp + kb * 32 + 4);
            u = __builtin_amdgcn_mfma_f32_16x16x32_f16(cvt8(x0, x1), winf[kb], u, 0, 0, 0);
        }
    }

    const int col = col0 + l15;
    unsigned int* sp = sent + bs * 64;    // 64 sentinels for this bs group
    const int mysent = cg * 8 + wave;
    _Float16* pw = slab + wave * 256;     // wave-private 512B transpose region
    const int li = lane * 2;              // ull index of this lane's 16B chunk

    for (int t = 1; t < T_; ++t) {
        f32x4 acc[4];
        acc[0] = u;
        acc[1] = f32x4{0.f, 0.f, 0.f, 0.f};
        acc[2] = f32x4{0.f, 0.f, 0.f, 0.f};
        acc[3] = f32x4{0.f, 0.f, 0.f, 0.f};

        if (t >= 2) {
            // ---- detect: one coalesced 4B/lane sentinel load per round
            const unsigned want = (unsigned)(t - 1);
            for (;;) {
                unsigned v = __hip_atomic_load(&sp[lane], __ATOMIC_RELAXED,
                                               __HIP_MEMORY_SCOPE_AGENT);
                if (__all((int)(v >= want))) break;
            }

            // ---- A-fragments direct from exch: 8 groups of 4 kbs,
            // register double-buffer, all indices compile-time static.
            const ull* ep = (const ull*)(exch + (size_t)(bs * 2 + ((t - 1) & 1)) * 16384);
            half8 ab[2][4];
            #pragma unroll
            for (int j = 0; j < 4; ++j) ab[0][j] = ldh8(ep, j, li);
            #pragma unroll
            for (int g = 0; g < 8; ++g) {
                if (g < 7) {
                    #pragma unroll
                    for (int j = 0; j < 4; ++j)
                        ab[(g + 1) & 1][j] = ldh8(ep, (g + 1) * 4 + j, li);
                }
                #pragma unroll
                for (int j = 0; j < 4; ++j)
                    acc[j] = __builtin_amdgcn_mfma_f32_16x16x32_f16(
                        ab[g & 1][j], wf[g * 4 + j], acc[j], 0, 0, 0);
            }
        }

        float v4[4];
        #pragma unroll
        for (int r = 0; r < 4; ++r)
            v4[r] = fast_tanh(acc[0][r] + acc[1][r] + acc[2][r] + acc[3][r]);

        // ---- publish: wave-private LDS transpose -> ONE coalesced 8B/lane
        // agent store into this wave's contiguous 512B frag-order region.
        // In-region half idx for (row m, cc): (cc>>3)*128 + m*8 + (cc&7);
        // lane i's 8B chunk = halves [4i, 4i+4). Region byte base = col0*32.
        asm volatile("s_waitcnt lgkmcnt(0)" ::: "memory");  // prev read done
        #pragma unroll
        for (int r = 0; r < 4; ++r)
            pw[(l15 >> 3) * 128 + (quad * 4 + r) * 8 + (l15 & 7)] = (_Float16)v4[r];
        asm volatile("s_waitcnt lgkmcnt(0)" ::: "memory");  // transpose visible
        ull chunk = *(const ull*)(pw + lane * 4);
        char* eb = (char*)exch + (size_t)(bs * 2 + (t & 1)) * 32768;
        __hip_atomic_store((ull*)(eb + (size_t)col0 * 32 + (size_t)lane * 8), chunk,
                           __ATOMIC_RELAXED, __HIP_MEMORY_SCOPE_AGENT);
        asm volatile("s_waitcnt vmcnt(0)" ::: "memory");    // ack wave's store
        if (lane == 0)
            __hip_atomic_store(&sp[mysent], (unsigned int)t,
                               __ATOMIC_RELAXED, __HIP_MEMORY_SCOPE_AGENT);

        // ---- off critical path: fp32 s_out + u_{t+1}
        #pragma unroll
        for (int r = 0; r < 4; ++r)
            s_out[(size_t)(crow + r) * T_ * N_ + (size_t)t * N_ + col] = v4[r];

        f32x4 un = {0.f, 0.f, 0.f, 0.f};
        if (t < T_ - 1) {
            const float* xp = X + ((size_t)arow * T_ + t) * DIN_ + quad * 8;
            #pragma unroll
            for (int kb = 0; kb < 8; ++kb) {
                float4 x0 = *(const float4*)(xp + kb * 32);
                float4 x1 = *(const float4*)(xp + kb * 32 + 4);
                un = __builtin_amdgcn_mfma_f32_16x16x32_f16(cvt8(x0, x1), winf[kb], un, 0, 0, 0);
            }
        }
        u = un;
    }
}

// ---------------------------------------------------------------------------
// Epilogue: out = s @ Wout + bout.  M=32768, N=128, K=1024.
// ---------------------------------------------------------------------------
__global__ __launch_bounds__(256, 2) void out_gemm(
    const float* __restrict__ s_in,   // [B*T][N]
    const float* __restrict__ Wout,   // [N][O]
    const float* __restrict__ bout,   // [O]
    float* __restrict__ outp)         // [B*T][O]
{
    const int m0   = blockIdx.x * 128;
    const int tid  = threadIdx.x;
    const int wave = tid >> 6;
    const int lane = tid & 63;
    const int l15  = lane & 15;
    const int quad = lane >> 4;

    __shared__ _Float16 WoT[128][40];

    f32x4 acc[2][8];
    #pragma unroll
    for (int mf = 0; mf < 2; ++mf)
        #pragma unroll
        for (int nt = 0; nt < 8; ++nt) acc[mf][nt] = f32x4{0.f, 0.f, 0.f, 0.f};
    float bv[8];
    #pragma unroll
    for (int nt = 0; nt < 8; ++nt) bv[nt] = bout[nt * 16 + l15];

    for (int kb = 0; kb < 32; ++kb) {
        __syncthreads();
        #pragma unroll
        for (int i = 0; i < 16; ++i) {
            int e = i * 256 + tid;
            int c = e & 127, kk = e >> 7;
            WoT[c][kk] = (_Float16)Wout[(size_t)(kb * 32 + kk) * O_ + c];
        }
        __syncthreads();

        #pragma unroll
        for (int mf = 0; mf < 2; ++mf) {
            const float* ap = s_in + (size_t)(m0 + wave * 32 + mf * 16 + l15) * N_ + kb * 32 + quad * 8;
            float4 a0 = *(const float4*)ap;
            float4 a1 = *(const float4*)(ap + 4);
            half8 a = cvt8(a0, a1);
            #pragma unroll
            for (int nt = 0; nt < 8; ++nt) {
                half8 b = *(const half8*)&WoT[nt * 16 + l15][quad * 8];
                acc[mf][nt] = __builtin_amdgcn_mfma_f32_16x16x32_f16(a, b, acc[mf][nt], 0, 0, 0);
            }
        }
    }

    #pragma unroll
    for (int mf = 0; mf < 2; ++mf) {
        float* op = outp + (size_t)(m0 + wave * 32 + mf * 16 + quad * 4) * O_ + l15;
        #pragma unroll
        for (int nt = 0; nt < 8; ++nt)
            #pragma unroll
            for (int r = 0; r < 4; ++r)
                op[(size_t)r * O_ + nt * 16] = acc[mf][nt][r] + bv[nt];
    }
}

extern "C" void kernel_launch(void* const* d_in, const int* in_sizes, int n_in,
                              void* d_out, int out_size, void* d_ws, size_t ws_size,
                              hipStream_t stream) {
    const float* X    = (const float*)d_in[0];   // [64][512][256]
    const float* Win  = (const float*)d_in[1];   // [256][1024]
    const float* W    = (const float*)d_in[2];   // [1024][1024]
    const float* Wout = (const float*)d_in[3];   // [1024][128]
    const float* bout = (const float*)d_in[4];   // [128]

    float* s_out = (float*)d_out;                 // [64][512][1024]
    float* outp  = s_out + (size_t)B_ * T_ * N_;  // [64][512][128]

    unsigned int* sent = (unsigned int*)d_ws;               // 256 uints
    _Float16* exch = (_Float16*)((char*)d_ws + 4096);       // 256 KB

    init_kernel<<<1, 256, 0, stream>>>(sent);
    rnn_kernel<<<32, 512, 0, stream>>>(X, W, Win, s_out, exch, sent);
    out_gemm<<<256, 256, 0, stream>>>(s_out, Wout, bout, outp);
}

// Round 6
// 4004.495 us; speedup vs baseline: 1.1980x; 1.1980x over previous
//
#include <hip/hip_runtime.h>

// Problem constants
#define B_ 64
#define T_ 512
#define DIN_ 256
#define N_ 1024
#define O_ 128

using half8 = __attribute__((ext_vector_type(8))) _Float16;
using f32x4 = __attribute__((ext_vector_type(4))) float;
typedef unsigned long long ull;

__device__ __forceinline__ half8 cvt8(float4 a, float4 b) {
    half8 h;
    h[0] = (_Float16)a.x; h[1] = (_Float16)a.y; h[2] = (_Float16)a.z; h[3] = (_Float16)a.w;
    h[4] = (_Float16)b.x; h[5] = (_Float16)b.y; h[6] = (_Float16)b.z; h[7] = (_Float16)b.w;
    return h;
}

__device__ __forceinline__ float fast_tanh(float x) {
    float ax = __builtin_fabsf(x);
    float e  = __expf(-2.0f * ax);
    float r  = __fdividef(1.0f - e, 1.0f + e);
    return x < 0.0f ? -r : r;
}

// ---------------------------------------------------------------------------
// Zero the 256 per-wave sentinels (only 4*64 used). Sentinels are monotone
// step tags; 0 never satisfies want >= 1, so no stale-accept across launches.
// ---------------------------------------------------------------------------
__global__ void init_kernel(unsigned int* sent) {
    sent[threadIdx.x] = 0u;
}

// ---------------------------------------------------------------------------
// Persistent recurrence, R6 = R2 skeleton + three latency cuts:
//  (A) SINGLE-POLLER DETECT: only wave0 polls the 64 global sentinels
//      (2-deep pipelined poll); it broadcasts the detected step via an LDS
//      flag; waves 1..7 spin on LDS (cheap). 8x less MALL poll traffic,
//      one detection sample instead of max-of-8 independent ones.
//      Freshness is a property of global time at the coherence point, so
//      whoever detects, the subsequent data loads (issued after the LDS
//      broadcast) observe complete data — same argument as R2.
//  (B) PING-PONG LDS SLAB, one barrier/step. WAR safety without the second
//      barrier: staging at step t+2 reuses the buffer read at step t; the
//      fast wave must pass barrier(t+1), which requires every wave to have
//      completed staging(t+1), which each wave does only after its own
//      ds_reads(t) — so no wave can overwrite a buffer another wave still
//      reads. The remaining barrier is the RAW lgkmcnt(0)+s_barrier.
//  (C) COALESCED PUBLISH + X-PREFETCH: wave-private LDS transpose (R5-
//      verified mapping) turns 4 scattered 2B stores/lane into ONE 8B
//      store/lane (wave's 512B frag-order region is contiguous), shrinking
//      the store drain before the sentinel. X[:,t+1,:] is prefetched into
//      registers at the tail (issue-only), and the u-GEMM MFMAs run inside
//      the slab-load latency bubble — the post-sentinel tail is ~100cy, so
//      wave0 reaches its poll almost immediately after publishing.
// Exchange layout (R0-verified): fp16, MFMA A-fragment order
// (half addr = kb*512 + lane*8 + j). Slab fetch: one-shot 8x8B agent
// atomic loads -> linear LDS writes -> conflict-free ds_read_b128.
// ---------------------------------------------------------------------------
__global__ __launch_bounds__(512, 1) void rnn_kernel(
    const float* __restrict__ X,      // [B][T][DIN]
    const float* __restrict__ W,      // [N][N]
    const float* __restrict__ Win,    // [DIN][N]
    float* __restrict__ s_out,        // [B][T][N]
    _Float16* __restrict__ exch,      // [4][2][16384] fp16, frag order
    unsigned int* __restrict__ sent)  // [4][64] per-wave sentinels
{
    const int bs   = blockIdx.x & 3;
    const int cg   = blockIdx.x >> 2;     // 0..7
    const int tid  = threadIdx.x;
    const int wave = tid >> 6;            // 0..7
    const int lane = tid & 63;
    const int l15  = lane & 15;
    const int quad = lane >> 4;
    const int col0 = cg * 128 + wave * 16;
    const int arow = bs * 16 + l15;       // A-frag batch row
    const int crow = bs * 16 + quad * 4;  // C-frag base batch row

    // smem: slab0 | slab1 | pub(8x256) | flag.  Setup staging (16x1032)
    // overlays slab0+head-of-slab1 (setup strictly precedes the loop).
    __shared__ __align__(16) _Float16 smem[2 * 16 * 1024 + 8 * 256 + 8];
    _Float16* slab0 = smem;
    _Float16* slab1 = smem + 16384;
    _Float16* pub   = smem + 32768;
    volatile int* fl = (volatile int*)(smem + 32768 + 2048);

    // ---- one-time: W B-fragments (8 passes, one per wave)
    half8 wf[32];
    for (int p = 0; p < 8; ++p) {
        const int c = tid & 15, k0 = tid >> 4;
        const int wc = cg * 128 + p * 16 + c;
        for (int k = k0; k < N_; k += 32)
            smem[c * 1032 + k] = (_Float16)W[(size_t)k * N_ + wc];
        __syncthreads();
        if (wave == p) {
            #pragma unroll
            for (int kb = 0; kb < 32; ++kb)
                wf[kb] = *(const half8*)&smem[l15 * 1032 + kb * 32 + quad * 8];
        }
        __syncthreads();
    }
    // ---- one-time: Win B-fragments
    half8 winf[8];
    for (int p = 0; p < 8; ++p) {
        const int c = tid & 15, k0 = tid >> 4;
        const int wc = cg * 128 + p * 16 + c;
        for (int k = k0; k < DIN_; k += 32)
            smem[c * 1032 + k] = (_Float16)Win[(size_t)k * N_ + wc];
        __syncthreads();
        if (wave == p) {
            #pragma unroll
            for (int kb = 0; kb < 8; ++kb)
                winf[kb] = *(const half8*)&smem[l15 * 1032 + kb * 32 + quad * 8];
        }
        __syncthreads();
    }
    if (tid == 0) *fl = 0;

    // ---- s[:,0,:] = 0 for this block's 16r x 128c slice
    #pragma unroll
    for (int i = 0; i < 4; ++i) {
        int e = i * 512 + tid;
        int r = e >> 7, c = e & 127;
        s_out[(size_t)(bs * 16 + r) * T_ * N_ + cg * 128 + c] = 0.0f;
    }
    __syncthreads();   // flag init + setup staging complete before loop

    // ---- u_1 = X[:,0,:] @ Win  (direct), prefetch X[:,1,:] into regs
    f32x4 u = {0.f, 0.f, 0.f, 0.f};
    float4 xr[16];
    {
        const float* xp = X + (size_t)arow * T_ * DIN_ + quad * 8;
        #pragma unroll
        for (int kb = 0; kb < 8; ++kb) {
            float4 x0 = *(const float4*)(xp + kb * 32);
            float4 x1 = *(const float4*)(xp + kb * 32 + 4);
            u = __builtin_amdgcn_mfma_f32_16x16x32_f16(cvt8(x0, x1), winf[kb], u, 0, 0, 0);
        }
        const float* xq = xp + DIN_;   // X[:,1,:]
        #pragma unroll
        for (int kb = 0; kb < 8; ++kb) {
            xr[2 * kb]     = *(const float4*)(xq + kb * 32);
            xr[2 * kb + 1] = *(const float4*)(xq + kb * 32 + 4);
        }
    }

    const int col = col0 + l15;
    unsigned int* sp = sent + bs * 64;    // 64 sentinels for this bs group
    const int mysent = cg * 8 + wave;
    _Float16* pw = pub + wave * 256;      // wave-private 512B transpose region

    for (int t = 1; t < T_; ++t) {
        f32x4 acc0 = u;
        f32x4 acc1 = {0.f, 0.f, 0.f, 0.f};
        f32x4 acc2 = {0.f, 0.f, 0.f, 0.f};
        f32x4 acc3 = {0.f, 0.f, 0.f, 0.f};
        f32x4 un   = {0.f, 0.f, 0.f, 0.f};
        _Float16* slab = ((t - 1) & 1) ? slab1 : slab0;

        if (t >= 2) {
            // ---- detect: wave0 polls global (2-deep), broadcasts via LDS
            const int want = t - 1;
            if (wave == 0) {
                unsigned va = __hip_atomic_load(&sp[lane], __ATOMIC_RELAXED,
                                                __HIP_MEMORY_SCOPE_AGENT);
                for (;;) {
                    unsigned vb = __hip_atomic_load(&sp[lane], __ATOMIC_RELAXED,
                                                    __HIP_MEMORY_SCOPE_AGENT);
                    if (__all((int)(va >= (unsigned)want))) break;
                    va = vb;
                }
                if (lane == 0) *fl = want;
            } else {
                while (*fl < want) { }
            }

            // ---- one-shot slab load: 8 x 8B/thread, all in flight at once
            const ull* ep = (const ull*)(exch + (size_t)(bs * 2 + ((t - 1) & 1)) * 16384);
            ull r0 = __hip_atomic_load(&ep[tid],        __ATOMIC_RELAXED, __HIP_MEMORY_SCOPE_AGENT);
            ull r1 = __hip_atomic_load(&ep[tid + 512],  __ATOMIC_RELAXED, __HIP_MEMORY_SCOPE_AGENT);
            ull r2 = __hip_atomic_load(&ep[tid + 1024], __ATOMIC_RELAXED, __HIP_MEMORY_SCOPE_AGENT);
            ull r3 = __hip_atomic_load(&ep[tid + 1536], __ATOMIC_RELAXED, __HIP_MEMORY_SCOPE_AGENT);
            ull r4 = __hip_atomic_load(&ep[tid + 2048], __ATOMIC_RELAXED, __HIP_MEMORY_SCOPE_AGENT);
            ull r5 = __hip_atomic_load(&ep[tid + 2560], __ATOMIC_RELAXED, __HIP_MEMORY_SCOPE_AGENT);
            ull r6 = __hip_atomic_load(&ep[tid + 3072], __ATOMIC_RELAXED, __HIP_MEMORY_SCOPE_AGENT);
            ull r7 = __hip_atomic_load(&ep[tid + 3584], __ATOMIC_RELAXED, __HIP_MEMORY_SCOPE_AGENT);

            // ---- u_{t+1} MFMAs inside the slab-load latency bubble
            if (t < T_ - 1) {
                #pragma unroll
                for (int kb = 0; kb < 8; ++kb)
                    un = __builtin_amdgcn_mfma_f32_16x16x32_f16(
                        cvt8(xr[2 * kb], xr[2 * kb + 1]), winf[kb], un, 0, 0, 0);
            }

            // ---- stage to LDS (linear 8B writes, conflict-free)
            ull* lp = (ull*)slab;
            lp[tid]        = r0;
            lp[tid + 512]  = r1;
            lp[tid + 1024] = r2;
            lp[tid + 1536] = r3;
            lp[tid + 2048] = r4;
            lp[tid + 2560] = r5;
            lp[tid + 3072] = r6;
            lp[tid + 3584] = r7;
            // RAW barrier: LDS visibility only — no vmcnt drain (B: only
            // barrier in the loop; WAR handled by ping-pong, see header)
            asm volatile("s_waitcnt lgkmcnt(0)\n\ts_barrier" ::: "memory");

            #pragma unroll
            for (int kb = 0; kb < 32; ++kb) {
                half8 a = *(const half8*)&slab[kb * 512 + lane * 8];
                if ((kb & 3) == 0)      acc0 = __builtin_amdgcn_mfma_f32_16x16x32_f16(a, wf[kb], acc0, 0, 0, 0);
                else if ((kb & 3) == 1) acc1 = __builtin_amdgcn_mfma_f32_16x16x32_f16(a, wf[kb], acc1, 0, 0, 0);
                else if ((kb & 3) == 2) acc2 = __builtin_amdgcn_mfma_f32_16x16x32_f16(a, wf[kb], acc2, 0, 0, 0);
                else                    acc3 = __builtin_amdgcn_mfma_f32_16x16x32_f16(a, wf[kb], acc3, 0, 0, 0);
            }
        } else {
            // t == 1: no recurrent term; just compute u_2 from prefetched X
            #pragma unroll
            for (int kb = 0; kb < 8; ++kb)
                un = __builtin_amdgcn_mfma_f32_16x16x32_f16(
                    cvt8(xr[2 * kb], xr[2 * kb + 1]), winf[kb], un, 0, 0, 0);
        }

        float v4[4];
        #pragma unroll
        for (int r = 0; r < 4; ++r)
            v4[r] = fast_tanh(acc0[r] + acc1[r] + acc2[r] + acc3[r]);

        // ---- publish: wave-private LDS transpose (R5-verified mapping) ->
        // ONE coalesced 8B/lane store into the wave's contiguous 512B
        // frag-order region -> ack own stores -> per-wave sentinel.
        asm volatile("s_waitcnt lgkmcnt(0)" ::: "memory");  // prev chunk read done
        #pragma unroll
        for (int r = 0; r < 4; ++r)
            pw[(l15 >> 3) * 128 + (quad * 4 + r) * 8 + (l15 & 7)] = (_Float16)v4[r];
        asm volatile("s_waitcnt lgkmcnt(0)" ::: "memory");  // transpose visible
        ull chunk = *(const ull*)(pw + lane * 4);
        char* eb = (char*)exch + (size_t)(bs * 2 + (t & 1)) * 32768;
        __hip_atomic_store((ull*)(eb + (size_t)col0 * 32 + (size_t)lane * 8), chunk,
                           __ATOMIC_RELAXED, __HIP_MEMORY_SCOPE_AGENT);
        asm volatile("s_waitcnt vmcnt(0)" ::: "memory");    // ack publish store
        if (lane == 0)
            __hip_atomic_store(&sp[mysent], (unsigned int)t,
                               __ATOMIC_RELAXED, __HIP_MEMORY_SCOPE_AGENT);

        // ---- tail (issue-only): fp32 s_out + X prefetch for t+1
        #pragma unroll
        for (int r = 0; r < 4; ++r)
            s_out[(size_t)(crow + r) * T_ * N_ + (size_t)t * N_ + col] = v4[r];

        if (t < T_ - 2) {
            const float* xq = X + ((size_t)arow * T_ + t + 1) * DIN_ + quad * 8;
            #pragma unroll
            for (int kb = 0; kb < 8; ++kb) {
                xr[2 * kb]     = *(const float4*)(xq + kb * 32);
                xr[2 * kb + 1] = *(const float4*)(xq + kb * 32 + 4);
            }
        }
        u = un;
    }
}

// ---------------------------------------------------------------------------
// Epilogue: out = s @ Wout + bout.  M=32768, N=128, K=1024.
// ---------------------------------------------------------------------------
__global__ __launch_bounds__(256, 2) void out_gemm(
    const float* __restrict__ s_in,   // [B*T][N]
    const float* __restrict__ Wout,   // [N][O]
    const float* __restrict__ bout,   // [O]
    float* __restrict__ outp)         // [B*T][O]
{
    const int m0   = blockIdx.x * 128;
    const int tid  = threadIdx.x;
    const int wave = tid >> 6;
    const int lane = tid & 63;
    const int l15  = lane & 15;
    const int quad = lane >> 4;

    __shared__ _Float16 WoT[128][40];

    f32x4 acc[2][8];
    #pragma unroll
    for (int mf = 0; mf < 2; ++mf)
        #pragma unroll
        for (int nt = 0; nt < 8; ++nt) acc[mf][nt] = f32x4{0.f, 0.f, 0.f, 0.f};
    float bv[8];
    #pragma unroll
    for (int nt = 0; nt < 8; ++nt) bv[nt] = bout[nt * 16 + l15];

    for (int kb = 0; kb < 32; ++kb) {
        __syncthreads();
        #pragma unroll
        for (int i = 0; i < 16; ++i) {
            int e = i * 256 + tid;
            int c = e & 127, kk = e >> 7;
            WoT[c][kk] = (_Float16)Wout[(size_t)(kb * 32 + kk) * O_ + c];
        }
        __syncthreads();

        #pragma unroll
        for (int mf = 0; mf < 2; ++mf) {
            const float* ap = s_in + (size_t)(m0 + wave * 32 + mf * 16 + l15) * N_ + kb * 32 + quad * 8;
            float4 a0 = *(const float4*)ap;
            float4 a1 = *(const float4*)(ap + 4);
            half8 a = cvt8(a0, a1);
            #pragma unroll
            for (int nt = 0; nt < 8; ++nt) {
                half8 b = *(const half8*)&WoT[nt * 16 + l15][quad * 8];
                acc[mf][nt] = __builtin_amdgcn_mfma_f32_16x16x32_f16(a, b, acc[mf][nt], 0, 0, 0);
            }
        }
    }

    #pragma unroll
    for (int mf = 0; mf < 2; ++mf) {
        float* op = outp + (size_t)(m0 + wave * 32 + mf * 16 + quad * 4) * O_ + l15;
        #pragma unroll
        for (int nt = 0; nt < 8; ++nt)
            #pragma unroll
            for (int r = 0; r < 4; ++r)
                op[(size_t)r * O_ + nt * 16] = acc[mf][nt][r] + bv[nt];
    }
}

extern "C" void kernel_launch(void* const* d_in, const int* in_sizes, int n_in,
                              void* d_out, int out_size, void* d_ws, size_t ws_size,
                              hipStream_t stream) {
    const float* X    = (const float*)d_in[0];   // [64][512][256]
    const float* Win  = (const float*)d_in[1];   // [256][1024]
    const float* W    = (const float*)d_in[2];   // [1024][1024]
    const float* Wout = (const float*)d_in[3];   // [1024][128]
    const float* bout = (const float*)d_in[4];   // [128]

    float* s_out = (float*)d_out;                 // [64][512][1024]
    float* outp  = s_out + (size_t)B_ * T_ * N_;  // [64][512][128]

    unsigned int* sent = (unsigned int*)d_ws;               // 256 uints
    _Float16* exch = (_Float16*)((char*)d_ws + 4096);       // 256 KB

    init_kernel<<<1, 256, 0, stream>>>(sent);
    rnn_kernel<<<32, 512, 0, stream>>>(X, W, Win, s_out, exch, sent);
    out_gemm<<<256, 256, 0, stream>>>(s_out, Wout, bout, outp);
}